// Round 1
// baseline (2160.601 us; speedup 1.0000x reference)
//
#include <hip/hip_runtime.h>

#define NN 20000
#define NE 320000
#define ZD 128

#define ACC_STEP(A, W) \
    acc[i][0] = fmaf((A), (W).x, acc[i][0]); \
    acc[i][1] = fmaf((A), (W).y, acc[i][1]); \
    acc[i][2] = fmaf((A), (W).z, acc[i][2]); \
    acc[i][3] = fmaf((A), (W).w, acc[i][3]);

// fs: [64 rows][LDW] LDS tile; W: row-major [SW][128] (already offset to slab base row)
// Each thread accumulates 8 rows (er..er+7) x 4 cols (zc..zc+3).
template<int LDW>
__device__ __forceinline__ void gemm_acc(const float (&fs)[64][LDW],
                                         const float* __restrict__ W,
                                         int SW, int zc, int er,
                                         float (&acc)[8][4])
{
    #pragma unroll 2
    for (int k = 0; k < SW; k += 4) {
        const float* wr = W + (size_t)k * ZD + zc;
        const float4 w0 = *(const float4*)(wr);
        const float4 w1 = *(const float4*)(wr + ZD);
        const float4 w2 = *(const float4*)(wr + 2 * ZD);
        const float4 w3 = *(const float4*)(wr + 3 * ZD);
        #pragma unroll
        for (int i = 0; i < 8; ++i) {
            const float4 a = *(const float4*)&fs[er + i][k];
            ACC_STEP(a.x, w0)
            ACC_STEP(a.y, w1)
            ACC_STEP(a.z, w2)
            ACC_STEP(a.w, w3)
        }
    }
}

__global__ __launch_bounds__(256) void count_kernel(const int* __restrict__ dst,
                                                    float* __restrict__ cnt)
{
    const int e = blockIdx.x * 256 + threadIdx.x;
    if (e < NE) atomicAdd(&cnt[dst[e]], 1.0f);
}

// One block = 64 edges. feat = [x_i | x_j-x_i | x_j*x_i | ea] built slab-by-slab in LDS.
// msg = relu(feat @ Wm + bm), scattered with atomicAdd into agg[dst].
template<int DIN>
__global__ __launch_bounds__(256, 4) void edge_msg(
    const float* __restrict__ x,     // [NN, DIN]
    const int* __restrict__ src,
    const int* __restrict__ dst,
    const float* __restrict__ ea,    // [NE, 4]
    const float* __restrict__ Wm,    // [3*DIN+4, 128]
    const float* __restrict__ bm,    // [128]
    float* __restrict__ agg)         // [NN, 128] (pre-zeroed)
{
    constexpr int LDW = DIN + 8;     // slab width DIN (+4 for ea at last slab) + pad
    __shared__ float fs[64][LDW];
    __shared__ int dst_s[64];
    const int t  = threadIdx.x;
    const int e0 = blockIdx.x * 64;
    const int zc = (t & 31) * 4;
    const int er = (t >> 5) * 8;
    float acc[8][4] = {};

    constexpr int TPR = DIN / 4;     // threads per row (float4 units)
    constexpr int RPI = 256 / TPR;   // rows staged per iteration
    const int lk = (t % TPR) * 4;
    const int r0 = t / TPR;

    if (t < 64) dst_s[t] = dst[e0 + t];

    #pragma unroll
    for (int s = 0; s < 3; ++s) {
        // ---- stage slab s ----
        for (int r = r0; r < 64; r += RPI) {
            const int e = e0 + r;
            float4 v;
            if (s == 0) {
                const int di = dst[e];
                v = *(const float4*)&x[(size_t)di * DIN + lk];
            } else {
                const int di = dst[e];
                const int sj = src[e];
                const float4 xi = *(const float4*)&x[(size_t)di * DIN + lk];
                const float4 xj = *(const float4*)&x[(size_t)sj * DIN + lk];
                if (s == 1) v = make_float4(xj.x - xi.x, xj.y - xi.y, xj.z - xi.z, xj.w - xi.w);
                else        v = make_float4(xj.x * xi.x, xj.y * xi.y, xj.z * xi.z, xj.w * xi.w);
            }
            *(float4*)&fs[r][lk] = v;
        }
        if (s == 2 && t < 64) {
            const float4 a = *(const float4*)&ea[(size_t)(e0 + t) * 4];
            fs[t][DIN + 0] = a.x; fs[t][DIN + 1] = a.y;
            fs[t][DIN + 2] = a.z; fs[t][DIN + 3] = a.w;
        }
        __syncthreads();
        // ---- GEMM on slab ----
        const int SW = (s == 2) ? (DIN + 4) : DIN;
        gemm_acc<LDW>(fs, Wm + (size_t)(s * DIN) * ZD, SW, zc, er, acc);
        __syncthreads();
    }

    // ---- bias + relu + scatter ----
    const float4 b = *(const float4*)&bm[zc];
    #pragma unroll
    for (int i = 0; i < 8; ++i) {
        float* ap = &agg[(size_t)dst_s[er + i] * ZD + zc];
        atomicAdd(ap + 0, fmaxf(acc[i][0] + b.x, 0.f));
        atomicAdd(ap + 1, fmaxf(acc[i][1] + b.y, 0.f));
        atomicAdd(ap + 2, fmaxf(acc[i][2] + b.z, 0.f));
        atomicAdd(ap + 3, fmaxf(acc[i][3] + b.w, 0.f));
    }
}

// out = relu([xin | agg/deg] @ Wf + bf)
template<int DIN>
__global__ __launch_bounds__(256, 4) void node_mlp(
    const float* __restrict__ xin,   // [NN, DIN]
    const float* __restrict__ agg,   // [NN, 128]
    const float* __restrict__ cnt,   // [NN]
    const float* __restrict__ Wf,    // [DIN+128, 128]
    const float* __restrict__ bf,
    float* __restrict__ xout)        // [NN, 128]
{
    constexpr int LDW = ZD + 8;
    __shared__ float fs[64][LDW];
    const int t  = threadIdx.x;
    const int n0 = blockIdx.x * 64;
    const int zc = (t & 31) * 4;
    const int er = (t >> 5) * 8;
    float acc[8][4] = {};

    {   // slab 0: xin
        constexpr int TPR = DIN / 4;
        constexpr int RPI = 256 / TPR;
        const int lk = (t % TPR) * 4;
        for (int r = t / TPR; r < 64; r += RPI) {
            const int n = n0 + r;
            float4 v = make_float4(0.f, 0.f, 0.f, 0.f);
            if (n < NN) v = *(const float4*)&xin[(size_t)n * DIN + lk];
            *(float4*)&fs[r][lk] = v;
        }
        __syncthreads();
        gemm_acc<LDW>(fs, Wf, DIN, zc, er, acc);
        __syncthreads();
    }
    {   // slab 1: agg * inv_deg
        const int lk = (t & 31) * 4;
        for (int r = t >> 5; r < 64; r += 8) {
            const int n = n0 + r;
            float4 v = make_float4(0.f, 0.f, 0.f, 0.f);
            if (n < NN) {
                const float inv = 1.0f / fmaxf(cnt[n], 1.0f);
                const float4 a = *(const float4*)&agg[(size_t)n * ZD + lk];
                v = make_float4(a.x * inv, a.y * inv, a.z * inv, a.w * inv);
            }
            *(float4*)&fs[r][lk] = v;
        }
        __syncthreads();
        gemm_acc<LDW>(fs, Wf + (size_t)DIN * ZD, ZD, zc, er, acc);
        __syncthreads();
    }

    const float4 b = *(const float4*)&bf[zc];
    #pragma unroll
    for (int i = 0; i < 8; ++i) {
        const int n = n0 + er + i;
        if (n < NN) {
            float4 o;
            o.x = fmaxf(acc[i][0] + b.x, 0.f);
            o.y = fmaxf(acc[i][1] + b.y, 0.f);
            o.z = fmaxf(acc[i][2] + b.z, 0.f);
            o.w = fmaxf(acc[i][3] + b.w, 0.f);
            *(float4*)&xout[(size_t)n * ZD + zc] = o;
        }
    }
}

// out = relu([x1|x2|x3] @ Wl + bl)
__global__ __launch_bounds__(256, 4) void fusion_kernel(
    const float* __restrict__ x1,
    const float* __restrict__ x2,
    const float* __restrict__ x3,
    const float* __restrict__ Wl,    // [384, 128]
    const float* __restrict__ bl,
    float* __restrict__ out)
{
    constexpr int LDW = ZD + 8;
    __shared__ float fs[64][LDW];
    const int t  = threadIdx.x;
    const int n0 = blockIdx.x * 64;
    const int zc = (t & 31) * 4;
    const int er = (t >> 5) * 8;
    float acc[8][4] = {};
    const float* srcs[3] = {x1, x2, x3};

    for (int s = 0; s < 3; ++s) {
        const float* xs = srcs[s];
        const int lk = (t & 31) * 4;
        for (int r = t >> 5; r < 64; r += 8) {
            const int n = n0 + r;
            float4 v = make_float4(0.f, 0.f, 0.f, 0.f);
            if (n < NN) v = *(const float4*)&xs[(size_t)n * ZD + lk];
            *(float4*)&fs[r][lk] = v;
        }
        __syncthreads();
        gemm_acc<LDW>(fs, Wl + (size_t)(s * ZD) * ZD, ZD, zc, er, acc);
        __syncthreads();
    }

    const float4 b = *(const float4*)&bl[zc];
    #pragma unroll
    for (int i = 0; i < 8; ++i) {
        const int n = n0 + er + i;
        if (n < NN) {
            float4 o;
            o.x = fmaxf(acc[i][0] + b.x, 0.f);
            o.y = fmaxf(acc[i][1] + b.y, 0.f);
            o.z = fmaxf(acc[i][2] + b.z, 0.f);
            o.w = fmaxf(acc[i][3] + b.w, 0.f);
            *(float4*)&out[(size_t)n * ZD + zc] = o;
        }
    }
}

extern "C" void kernel_launch(void* const* d_in, const int* in_sizes, int n_in,
                              void* d_out, int out_size, void* d_ws, size_t ws_size,
                              hipStream_t stream)
{
    (void)in_sizes; (void)n_in; (void)out_size; (void)ws_size;

    const float* x   = (const float*)d_in[0];
    const int*   ei  = (const int*)d_in[1];
    const float* ea  = (const float*)d_in[2];
    const float* Wm1 = (const float*)d_in[3];  const float* bm1 = (const float*)d_in[4];
    const float* Wf1 = (const float*)d_in[5];  const float* bf1 = (const float*)d_in[6];
    const float* Wm2 = (const float*)d_in[7];  const float* bm2 = (const float*)d_in[8];
    const float* Wf2 = (const float*)d_in[9];  const float* bf2 = (const float*)d_in[10];
    const float* Wm3 = (const float*)d_in[11]; const float* bm3 = (const float*)d_in[12];
    const float* Wf3 = (const float*)d_in[13]; const float* bf3 = (const float*)d_in[14];
    const float* Wl  = (const float*)d_in[15]; const float* bl  = (const float*)d_in[16];

    const int* src = ei;           // edge_index[0]
    const int* dst = ei + NE;      // edge_index[1]

    // workspace layout (floats): cnt[20480 pad] | agg[NN*ZD] | x1 | x2 | x3  (~41 MB)
    float* cnt = (float*)d_ws;
    float* agg = cnt + 20480;
    float* x1  = agg + (size_t)NN * ZD;
    float* x2  = x1  + (size_t)NN * ZD;
    float* x3  = x2  + (size_t)NN * ZD;
    float* out = (float*)d_out;

    const size_t aggBytes = (size_t)NN * ZD * sizeof(float);

    // zero cnt+agg (contiguous), then degree count (shared across all 3 convs)
    hipMemsetAsync(cnt, 0, 20480 * sizeof(float) + aggBytes, stream);
    count_kernel<<<NE / 256, 256, 0, stream>>>(dst, cnt);

    const int EG = NE / 64;                 // 5000 edge blocks (exact)
    const int NG = (NN + 63) / 64;          // 313 node blocks

    // conv1
    edge_msg<64><<<EG, 256, 0, stream>>>(x, src, dst, ea, Wm1, bm1, agg);
    node_mlp<64><<<NG, 256, 0, stream>>>(x, agg, cnt, Wf1, bf1, x1);

    // conv2
    hipMemsetAsync(agg, 0, aggBytes, stream);
    edge_msg<128><<<EG, 256, 0, stream>>>(x1, src, dst, ea, Wm2, bm2, agg);
    node_mlp<128><<<NG, 256, 0, stream>>>(x1, agg, cnt, Wf2, bf2, x2);

    // conv3
    hipMemsetAsync(agg, 0, aggBytes, stream);
    edge_msg<128><<<EG, 256, 0, stream>>>(x2, src, dst, ea, Wm3, bm3, agg);
    node_mlp<128><<<NG, 256, 0, stream>>>(x2, agg, cnt, Wf3, bf3, x3);

    // fusion
    fusion_kernel<<<NG, 256, 0, stream>>>(x1, x2, x3, Wl, bl, out);
}

// Round 5
// 1312.998 us; speedup vs baseline: 1.6455x; 1.6455x over previous
//
#include <hip/hip_runtime.h>

#define NN 20000
#define NE 320000
#define ZD 128

#define ACC_STEP(A, W) \
    acc[i][0] = fmaf((A), (W).x, acc[i][0]); \
    acc[i][1] = fmaf((A), (W).y, acc[i][1]); \
    acc[i][2] = fmaf((A), (W).z, acc[i][2]); \
    acc[i][3] = fmaf((A), (W).w, acc[i][3]);

// fs: [64 rows][LDW] LDS tile; W: row-major [SW][128] (already offset to slab base row)
// Each thread accumulates 8 rows (er..er+7) x 4 cols (zc..zc+3).
template<int LDW>
__device__ __forceinline__ void gemm_acc(const float (&fs)[64][LDW],
                                         const float* __restrict__ W,
                                         int SW, int zc, int er,
                                         float (&acc)[8][4])
{
    #pragma unroll 2
    for (int k = 0; k < SW; k += 4) {
        const float* wr = W + (size_t)k * ZD + zc;
        const float4 w0 = *(const float4*)(wr);
        const float4 w1 = *(const float4*)(wr + ZD);
        const float4 w2 = *(const float4*)(wr + 2 * ZD);
        const float4 w3 = *(const float4*)(wr + 3 * ZD);
        #pragma unroll
        for (int i = 0; i < 8; ++i) {
            const float4 a = *(const float4*)&fs[er + i][k];
            ACC_STEP(a.x, w0)
            ACC_STEP(a.y, w1)
            ACC_STEP(a.z, w2)
            ACC_STEP(a.w, w3)
        }
    }
}

// ---------------- counting sort by dst ----------------

__global__ __launch_bounds__(256) void hist_kernel(const int* __restrict__ dst,
                                                   int* __restrict__ hist)
{
    const int e = blockIdx.x * 256 + threadIdx.x;
    if (e < NE) atomicAdd(&hist[dst[e]], 1);
}

// single block: exclusive prefix sum over hist[NN] -> curs (scatter cursors)
__global__ __launch_bounds__(1024) void scan_kernel(const int* __restrict__ hist,
                                                    int* __restrict__ curs)
{
    __shared__ int tmp[1024];
    __shared__ int carry;
    const int t = threadIdx.x;
    if (t == 0) carry = 0;
    __syncthreads();
    for (int base = 0; base < NN; base += 1024) {
        const int i = base + t;
        const int v = (i < NN) ? hist[i] : 0;
        tmp[t] = v;
        __syncthreads();
        for (int off = 1; off < 1024; off <<= 1) {
            const int u = (t >= off) ? tmp[t - off] : 0;
            __syncthreads();
            tmp[t] += u;
            __syncthreads();
        }
        const int incl = tmp[t];
        if (i < NN) curs[i] = carry + incl - v;
        __syncthreads();
        if (t == 1023) carry += incl;
        __syncthreads();
    }
}

__global__ __launch_bounds__(256) void scatter_kernel(
    const int* __restrict__ src, const int* __restrict__ dst,
    int* __restrict__ curs,
    int* __restrict__ src_s, int* __restrict__ dst_s, int* __restrict__ perm)
{
    const int e = blockIdx.x * 256 + threadIdx.x;
    if (e < NE) {
        const int d = dst[e];
        const int p = atomicAdd(&curs[d], 1);
        src_s[p] = src[e];
        dst_s[p] = d;
        perm[p] = e;
    }
}

// ---------------- fused message GEMM + scatter (sorted edges) ----------------

template<int DIN>
__global__ __launch_bounds__(256, 4) void edge_msg(
    const float* __restrict__ x,     // [NN, DIN]
    const int* __restrict__ src_s,
    const int* __restrict__ dst_s,   // sorted (non-decreasing)
    const int* __restrict__ perm,    // sorted pos -> original edge id
    const float4* __restrict__ ea,   // original order [NE]
    const float* __restrict__ Wm,    // [3*DIN+4, 128]
    const float* __restrict__ bm,
    float* __restrict__ agg)         // [NN, 128] (pre-zeroed)
{
    constexpr int LDW = DIN + 8;
    __shared__ float fs[64][LDW];
    const int t  = threadIdx.x;
    const int e0 = blockIdx.x * 64;
    const int zc = (t & 31) * 4;
    const int er = (t >> 5) * 8;
    float acc[8][4] = {};

    constexpr int TPR = DIN / 4;
    constexpr int RPI = 256 / TPR;
    const int lk = (t % TPR) * 4;
    const int r0 = t / TPR;

    #pragma unroll
    for (int s = 0; s < 3; ++s) {
        for (int r = r0; r < 64; r += RPI) {
            const int e = e0 + r;
            const int di = dst_s[e];
            float4 v;
            if (s == 0) {
                v = *(const float4*)&x[(size_t)di * DIN + lk];
            } else {
                const int sj = src_s[e];
                const float4 xi = *(const float4*)&x[(size_t)di * DIN + lk];
                const float4 xj = *(const float4*)&x[(size_t)sj * DIN + lk];
                if (s == 1) v = make_float4(xj.x - xi.x, xj.y - xi.y, xj.z - xi.z, xj.w - xi.w);
                else        v = make_float4(xj.x * xi.x, xj.y * xi.y, xj.z * xi.z, xj.w * xi.w);
            }
            *(float4*)&fs[r][lk] = v;
        }
        if (s == 2 && t < 64) {
            const float4 a = ea[perm[e0 + t]];
            fs[t][DIN + 0] = a.x; fs[t][DIN + 1] = a.y;
            fs[t][DIN + 2] = a.z; fs[t][DIN + 3] = a.w;
        }
        __syncthreads();
        gemm_acc<LDW>(fs, Wm + (size_t)(s * DIN) * ZD, (s == 2) ? DIN + 4 : DIN, zc, er, acc);
        __syncthreads();
    }

    // bias + relu + run-reduced atomic scatter (sorted dst => register runs)
    const float4 b = *(const float4*)&bm[zc];
    const int* dr = dst_s + e0 + er;
    int cur = dr[0];
    float sx = fmaxf(acc[0][0] + b.x, 0.f);
    float sy = fmaxf(acc[0][1] + b.y, 0.f);
    float sz = fmaxf(acc[0][2] + b.z, 0.f);
    float sw = fmaxf(acc[0][3] + b.w, 0.f);
    #pragma unroll
    for (int i = 1; i < 8; ++i) {
        const int d = dr[i];
        const float vx = fmaxf(acc[i][0] + b.x, 0.f);
        const float vy = fmaxf(acc[i][1] + b.y, 0.f);
        const float vz = fmaxf(acc[i][2] + b.z, 0.f);
        const float vw = fmaxf(acc[i][3] + b.w, 0.f);
        if (d == cur) {
            sx += vx; sy += vy; sz += vz; sw += vw;
        } else {
            float* ap = &agg[(size_t)cur * ZD + zc];
            atomicAdd(ap + 0, sx); atomicAdd(ap + 1, sy);
            atomicAdd(ap + 2, sz); atomicAdd(ap + 3, sw);
            cur = d; sx = vx; sy = vy; sz = vz; sw = vw;
        }
    }
    float* ap = &agg[(size_t)cur * ZD + zc];
    atomicAdd(ap + 0, sx); atomicAdd(ap + 1, sy);
    atomicAdd(ap + 2, sz); atomicAdd(ap + 3, sw);
}

// ---------------- node MLP: out = relu([xin | agg/deg] @ Wf + bf) ----------------

template<int DIN>
__global__ __launch_bounds__(256, 4) void node_mlp(
    const float* __restrict__ xin,   // [NN, DIN]
    const float* __restrict__ agg,   // [NN, 128]
    const int* __restrict__ deg,     // [NN]
    const float* __restrict__ Wf,    // [DIN+128, 128]
    const float* __restrict__ bf,
    float* __restrict__ xout)        // [NN, 128]
{
    constexpr int LDW = ZD + 8;
    __shared__ float fs[64][LDW];
    const int t  = threadIdx.x;
    const int n0 = blockIdx.x * 64;
    const int zc = (t & 31) * 4;
    const int er = (t >> 5) * 8;
    float acc[8][4] = {};

    {   // slab 0: xin
        constexpr int TPR = DIN / 4;
        constexpr int RPI = 256 / TPR;
        const int lk = (t % TPR) * 4;
        for (int r = t / TPR; r < 64; r += RPI) {
            const int n = n0 + r;
            float4 v = make_float4(0.f, 0.f, 0.f, 0.f);
            if (n < NN) v = *(const float4*)&xin[(size_t)n * DIN + lk];
            *(float4*)&fs[r][lk] = v;
        }
        __syncthreads();
        gemm_acc<LDW>(fs, Wf, DIN, zc, er, acc);
        __syncthreads();
    }
    {   // slab 1: agg * inv_deg
        const int lk = (t & 31) * 4;
        for (int r = t >> 5; r < 64; r += 8) {
            const int n = n0 + r;
            float4 v = make_float4(0.f, 0.f, 0.f, 0.f);
            if (n < NN) {
                const float inv = 1.0f / fmaxf((float)deg[n], 1.0f);
                const float4 a = *(const float4*)&agg[(size_t)n * ZD + lk];
                v = make_float4(a.x * inv, a.y * inv, a.z * inv, a.w * inv);
            }
            *(float4*)&fs[r][lk] = v;
        }
        __syncthreads();
        gemm_acc<LDW>(fs, Wf + (size_t)DIN * ZD, ZD, zc, er, acc);
        __syncthreads();
    }

    const float4 b = *(const float4*)&bf[zc];
    #pragma unroll
    for (int i = 0; i < 8; ++i) {
        const int n = n0 + er + i;
        if (n < NN) {
            float4 o;
            o.x = fmaxf(acc[i][0] + b.x, 0.f);
            o.y = fmaxf(acc[i][1] + b.y, 0.f);
            o.z = fmaxf(acc[i][2] + b.z, 0.f);
            o.w = fmaxf(acc[i][3] + b.w, 0.f);
            *(float4*)&xout[(size_t)n * ZD + zc] = o;
        }
    }
}

// ---------------- fusion: out = relu([x1|x2|x3] @ Wl + bl) ----------------

__global__ __launch_bounds__(256, 4) void fusion_kernel(
    const float* __restrict__ x1,
    const float* __restrict__ x2,
    const float* __restrict__ x3,    // == out (in-place safe: blocks touch own rows only)
    const float* __restrict__ Wl,    // [384, 128]
    const float* __restrict__ bl,
    float* __restrict__ out)
{
    constexpr int LDW = ZD + 8;
    __shared__ float fs[64][LDW];
    const int t  = threadIdx.x;
    const int n0 = blockIdx.x * 64;
    const int zc = (t & 31) * 4;
    const int er = (t >> 5) * 8;
    float acc[8][4] = {};
    const float* srcs[3] = {x1, x2, x3};

    for (int s = 0; s < 3; ++s) {
        const float* xs = srcs[s];
        const int lk = (t & 31) * 4;
        for (int r = t >> 5; r < 64; r += 8) {
            const int n = n0 + r;
            float4 v = make_float4(0.f, 0.f, 0.f, 0.f);
            if (n < NN) v = *(const float4*)&xs[(size_t)n * ZD + lk];
            *(float4*)&fs[r][lk] = v;
        }
        __syncthreads();
        gemm_acc<LDW>(fs, Wl + (size_t)(s * ZD) * ZD, ZD, zc, er, acc);
        __syncthreads();
    }

    const float4 b = *(const float4*)&bl[zc];
    #pragma unroll
    for (int i = 0; i < 8; ++i) {
        const int n = n0 + er + i;
        if (n < NN) {
            float4 o;
            o.x = fmaxf(acc[i][0] + b.x, 0.f);
            o.y = fmaxf(acc[i][1] + b.y, 0.f);
            o.z = fmaxf(acc[i][2] + b.z, 0.f);
            o.w = fmaxf(acc[i][3] + b.w, 0.f);
            *(float4*)&out[(size_t)n * ZD + zc] = o;
        }
    }
}

extern "C" void kernel_launch(void* const* d_in, const int* in_sizes, int n_in,
                              void* d_out, int out_size, void* d_ws, size_t ws_size,
                              hipStream_t stream)
{
    (void)in_sizes; (void)n_in; (void)out_size; (void)ws_size;

    const float* x   = (const float*)d_in[0];
    const int*   ei  = (const int*)d_in[1];
    const float* ea  = (const float*)d_in[2];
    const float* Wm1 = (const float*)d_in[3];  const float* bm1 = (const float*)d_in[4];
    const float* Wf1 = (const float*)d_in[5];  const float* bf1 = (const float*)d_in[6];
    const float* Wm2 = (const float*)d_in[7];  const float* bm2 = (const float*)d_in[8];
    const float* Wf2 = (const float*)d_in[9];  const float* bf2 = (const float*)d_in[10];
    const float* Wm3 = (const float*)d_in[11]; const float* bm3 = (const float*)d_in[12];
    const float* Wf3 = (const float*)d_in[13]; const float* bf3 = (const float*)d_in[14];
    const float* Wl  = (const float*)d_in[15]; const float* bl  = (const float*)d_in[16];

    const int* src = ei;           // edge_index[0]
    const int* dst = ei + NE;      // edge_index[1]

    // workspace (~35 MB, all 16B-aligned at block starts):
    // agg[NN*ZD] | x1[NN*ZD] | x2[NN*ZD] | hist[20480] | curs[20480] | src_s[NE] | dst_s[NE] | perm[NE]
    float* agg  = (float*)d_ws;
    float* x1   = agg + (size_t)NN * ZD;
    float* x2   = x1  + (size_t)NN * ZD;
    int*   hist = (int*)(x2 + (size_t)NN * ZD);
    int*   curs = hist + 20480;
    int*   src_s = curs + 20480;
    int*   dst_s = src_s + NE;
    int*   perm  = dst_s + NE;
    float* x3   = (float*)d_out;   // in-place through fusion
    float* out  = (float*)d_out;

    const size_t aggBytes = (size_t)NN * ZD * sizeof(float);

    // ---- counting sort by dst (hist doubles as degree for the mean) ----
    hipMemsetAsync(hist, 0, 20480 * sizeof(int), stream);
    hist_kernel<<<(NE + 255) / 256, 256, 0, stream>>>(dst, hist);
    scan_kernel<<<1, 1024, 0, stream>>>(hist, curs);
    scatter_kernel<<<(NE + 255) / 256, 256, 0, stream>>>(src, dst, curs, src_s, dst_s, perm);

    const int EG = NE / 64;                 // 5000 edge blocks (exact)
    const int NG = (NN + 63) / 64;          // 313 node blocks

    // conv1
    hipMemsetAsync(agg, 0, aggBytes, stream);
    edge_msg<64><<<EG, 256, 0, stream>>>(x, src_s, dst_s, perm, (const float4*)ea, Wm1, bm1, agg);
    node_mlp<64><<<NG, 256, 0, stream>>>(x, agg, hist, Wf1, bf1, x1);

    // conv2
    hipMemsetAsync(agg, 0, aggBytes, stream);
    edge_msg<128><<<EG, 256, 0, stream>>>(x1, src_s, dst_s, perm, (const float4*)ea, Wm2, bm2, agg);
    node_mlp<128><<<NG, 256, 0, stream>>>(x1, agg, hist, Wf2, bf2, x2);

    // conv3
    hipMemsetAsync(agg, 0, aggBytes, stream);
    edge_msg<128><<<EG, 256, 0, stream>>>(x2, src_s, dst_s, perm, (const float4*)ea, Wm3, bm3, agg);
    node_mlp<128><<<NG, 256, 0, stream>>>(x2, agg, hist, Wf3, bf3, x3);

    // fusion (x3 lives in d_out; blocks read/write only their own rows)
    fusion_kernel<<<NG, 256, 0, stream>>>(x1, x2, x3, Wl, bl, out);
}

// Round 6
// 1029.502 us; speedup vs baseline: 2.0987x; 1.2754x over previous
//
#include <hip/hip_runtime.h>

#define NN 20000
#define NE 320000
#define ZD 128

typedef __attribute__((ext_vector_type(8))) short s16x8;
typedef __attribute__((ext_vector_type(4))) float f32x4;

#define MFMA16(A, B, C) __builtin_amdgcn_mfma_f32_16x16x32_bf16((A), (B), (C), 0, 0, 0)

__device__ __forceinline__ unsigned short bf16_rne(float v) {
    unsigned int u = __float_as_uint(v);
    unsigned int r = u + 0x7FFFu + ((u >> 16) & 1u);
    return (unsigned short)(r >> 16);
}
__device__ __forceinline__ float bf16f(unsigned short h) {
    return __uint_as_float(((unsigned int)h) << 16);
}

// ---------------- fp32 LDS-tile GEMM helper (node_mlp / fusion, unchanged) ----------------

#define ACC_STEP(A, W) \
    acc[i][0] = fmaf((A), (W).x, acc[i][0]); \
    acc[i][1] = fmaf((A), (W).y, acc[i][1]); \
    acc[i][2] = fmaf((A), (W).z, acc[i][2]); \
    acc[i][3] = fmaf((A), (W).w, acc[i][3]);

template<int LDW>
__device__ __forceinline__ void gemm_acc(const float (&fs)[64][LDW],
                                         const float* __restrict__ W,
                                         int SW, int zc, int er,
                                         float (&acc)[8][4])
{
    #pragma unroll 2
    for (int k = 0; k < SW; k += 4) {
        const float* wr = W + (size_t)k * ZD + zc;
        const float4 w0 = *(const float4*)(wr);
        const float4 w1 = *(const float4*)(wr + ZD);
        const float4 w2 = *(const float4*)(wr + 2 * ZD);
        const float4 w3 = *(const float4*)(wr + 3 * ZD);
        #pragma unroll
        for (int i = 0; i < 8; ++i) {
            const float4 a = *(const float4*)&fs[er + i][k];
            ACC_STEP(a.x, w0)
            ACC_STEP(a.y, w1)
            ACC_STEP(a.z, w2)
            ACC_STEP(a.w, w3)
        }
    }
}

// ---------------- counting sort by dst (validated R5) ----------------

__global__ __launch_bounds__(256) void hist_kernel(const int* __restrict__ dst,
                                                   int* __restrict__ hist)
{
    const int e = blockIdx.x * 256 + threadIdx.x;
    if (e < NE) atomicAdd(&hist[dst[e]], 1);
}

__global__ __launch_bounds__(1024) void scan_kernel(const int* __restrict__ hist,
                                                    int* __restrict__ curs)
{
    __shared__ int tmp[1024];
    __shared__ int carry;
    const int t = threadIdx.x;
    if (t == 0) carry = 0;
    __syncthreads();
    for (int base = 0; base < NN; base += 1024) {
        const int i = base + t;
        const int v = (i < NN) ? hist[i] : 0;
        tmp[t] = v;
        __syncthreads();
        for (int off = 1; off < 1024; off <<= 1) {
            const int u = (t >= off) ? tmp[t - off] : 0;
            __syncthreads();
            tmp[t] += u;
            __syncthreads();
        }
        const int incl = tmp[t];
        if (i < NN) curs[i] = carry + incl - v;
        __syncthreads();
        if (t == 1023) carry += incl;
        __syncthreads();
    }
}

__global__ __launch_bounds__(256) void scatter_kernel(
    const int* __restrict__ src, const int* __restrict__ dst,
    int* __restrict__ curs,
    int* __restrict__ src_s, int* __restrict__ dst_s, int* __restrict__ perm)
{
    const int e = blockIdx.x * 256 + threadIdx.x;
    if (e < NE) {
        const int d = dst[e];
        const int p = atomicAdd(&curs[d], 1);
        src_s[p] = src[e];
        dst_s[p] = d;
        perm[p] = e;
    }
}

// ---------------- weight packing into MFMA B-fragment order (hi/lo bf16) ----------------
// frag id f = (ks*8 + ct)*64 + lane ; lane holds B[k = ks*32+(lane>>4)*8 + i][col = ct*16+(lane&15)]

__global__ __launch_bounds__(256) void pack_w(const float* __restrict__ W, int K, int total,
                                              unsigned short* __restrict__ Bh,
                                              unsigned short* __restrict__ Bl)
{
    const int f = blockIdx.x * 256 + threadIdx.x;
    if (f >= total) return;
    const int lane = f & 63;
    const int ct = (f >> 6) & 7;
    const int ks = f >> 9;
    const int k0 = ks * 32 + (lane >> 4) * 8;
    const int col = ct * 16 + (lane & 15);
    unsigned short* oh = Bh + (size_t)f * 8;
    unsigned short* ol = Bl + (size_t)f * 8;
    #pragma unroll
    for (int i = 0; i < 8; ++i) {
        const int k = k0 + i;
        const float v = (k < K) ? W[(size_t)k * ZD + col] : 0.f;
        const unsigned short h = bf16_rne(v);
        oh[i] = h;
        ol[i] = bf16_rne(v - bf16f(h));
    }
}

// ---------------- MFMA split-bf16 message GEMM + run-reduced scatter ----------------
// feat = [x_i | x_j-x_i | x_j*x_i | ea], K padded to NSLAB*64+32.
// Block: 64 sorted edges x 128 out cols. 4 waves, each 16 rows x 8 col-tiles (16x16x32 MFMA).

template<int DIN>
__global__ __launch_bounds__(256, 4) void edge_msg_mfma(
    const float* __restrict__ x,     // [NN, DIN]
    const int* __restrict__ src_s,
    const int* __restrict__ dst_s,   // sorted
    const int* __restrict__ perm,
    const float4* __restrict__ ea,
    const unsigned short* __restrict__ Bh,  // packed hi
    const unsigned short* __restrict__ Bl,  // packed lo
    const float* __restrict__ bm,
    float* __restrict__ agg)
{
    constexpr int NSLAB = 3 * DIN / 64;
    __shared__ unsigned short fsh[64][72];
    __shared__ unsigned short fsl[64][72];
    __shared__ int dsh[64];
    const int t = threadIdx.x;
    const int e0 = blockIdx.x * 64;
    const int lane = t & 63;
    const int w = t >> 6;

    f32x4 acc[8];
    #pragma unroll
    for (int ct = 0; ct < 8; ++ct) acc[ct] = (f32x4){0.f, 0.f, 0.f, 0.f};

    if (t < 64) dsh[t] = dst_s[e0 + t];

    const int ar = w * 16 + (lane & 15);   // A-fragment row (edge within block)
    const int g  = lane >> 4;              // k-octet selector

    const int sc4 = (t & 15) * 4;          // staging: 16 threads/row, 4 cols each
    const int sr0 = t >> 4;

    for (int s = 0; s < NSLAB; ++s) {
        const int kind = (s * 64) / DIN;
        const int col0 = (s * 64) % DIN;
        // ---- stage 64x64 slab as bf16 hi/lo ----
        #pragma unroll
        for (int p = 0; p < 4; ++p) {
            const int r = sr0 + p * 16;
            const int e = e0 + r;
            float4 v;
            if (kind == 0) {
                v = *(const float4*)&x[(size_t)dst_s[e] * DIN + col0 + sc4];
            } else {
                const float4 xi = *(const float4*)&x[(size_t)dst_s[e] * DIN + col0 + sc4];
                const float4 xj = *(const float4*)&x[(size_t)src_s[e] * DIN + col0 + sc4];
                if (kind == 1) v = make_float4(xj.x - xi.x, xj.y - xi.y, xj.z - xi.z, xj.w - xi.w);
                else           v = make_float4(xj.x * xi.x, xj.y * xi.y, xj.z * xi.z, xj.w * xi.w);
            }
            const float vv[4] = {v.x, v.y, v.z, v.w};
            unsigned int hp[2], lp[2];
            #pragma unroll
            for (int q = 0; q < 2; ++q) {
                const unsigned short h0 = bf16_rne(vv[2*q]);
                const unsigned short h1 = bf16_rne(vv[2*q+1]);
                const unsigned short l0 = bf16_rne(vv[2*q]   - bf16f(h0));
                const unsigned short l1 = bf16_rne(vv[2*q+1] - bf16f(h1));
                hp[q] = (unsigned int)h0 | ((unsigned int)h1 << 16);
                lp[q] = (unsigned int)l0 | ((unsigned int)l1 << 16);
            }
            *(uint2*)&fsh[r][sc4] = make_uint2(hp[0], hp[1]);
            *(uint2*)&fsl[r][sc4] = make_uint2(lp[0], lp[1]);
        }
        __syncthreads();
        // ---- 2 K-steps of 32 ----
        #pragma unroll
        for (int kl = 0; kl < 2; ++kl) {
            const int ks = s * 2 + kl;
            const s16x8 ah = *(const s16x8*)&fsh[ar][kl * 32 + g * 8];
            const s16x8 al = *(const s16x8*)&fsl[ar][kl * 32 + g * 8];
            const unsigned short* bhp = Bh + ((size_t)ks * 512 + lane) * 8;
            const unsigned short* blp = Bl + ((size_t)ks * 512 + lane) * 8;
            #pragma unroll
            for (int ct = 0; ct < 8; ++ct) {
                const s16x8 bh = *(const s16x8*)(bhp + (size_t)ct * 512);
                const s16x8 bl = *(const s16x8*)(blp + (size_t)ct * 512);
                acc[ct] = MFMA16(al, bh, acc[ct]);
                acc[ct] = MFMA16(ah, bl, acc[ct]);
                acc[ct] = MFMA16(ah, bh, acc[ct]);
            }
        }
        __syncthreads();
    }

    // ---- final K-step: ea (4 real cols + 28 zero) ----
    {
        const int r = t >> 2, c8 = (t & 3) * 8;
        unsigned int hw[4] = {0, 0, 0, 0}, lw[4] = {0, 0, 0, 0};
        if (c8 == 0) {
            const float4 a = ea[perm[e0 + r]];
            const float vv[4] = {a.x, a.y, a.z, a.w};
            #pragma unroll
            for (int q = 0; q < 2; ++q) {
                const unsigned short h0 = bf16_rne(vv[2*q]);
                const unsigned short h1 = bf16_rne(vv[2*q+1]);
                const unsigned short l0 = bf16_rne(vv[2*q]   - bf16f(h0));
                const unsigned short l1 = bf16_rne(vv[2*q+1] - bf16f(h1));
                hw[q] = (unsigned int)h0 | ((unsigned int)h1 << 16);
                lw[q] = (unsigned int)l0 | ((unsigned int)l1 << 16);
            }
        }
        *(uint4*)&fsh[r][c8] = make_uint4(hw[0], hw[1], hw[2], hw[3]);
        *(uint4*)&fsl[r][c8] = make_uint4(lw[0], lw[1], lw[2], lw[3]);
        __syncthreads();
        const int ks = NSLAB * 2;
        const s16x8 ah = *(const s16x8*)&fsh[ar][g * 8];
        const s16x8 al = *(const s16x8*)&fsl[ar][g * 8];
        const unsigned short* bhp = Bh + ((size_t)ks * 512 + lane) * 8;
        const unsigned short* blp = Bl + ((size_t)ks * 512 + lane) * 8;
        #pragma unroll
        for (int ct = 0; ct < 8; ++ct) {
            const s16x8 bh = *(const s16x8*)(bhp + (size_t)ct * 512);
            const s16x8 bl = *(const s16x8*)(blp + (size_t)ct * 512);
            acc[ct] = MFMA16(al, bh, acc[ct]);
            acc[ct] = MFMA16(ah, bl, acc[ct]);
            acc[ct] = MFMA16(ah, bh, acc[ct]);
        }
    }

    // ---- bias + relu + run-reduced atomic scatter ----
    // C/D layout: col = ct*16 + (lane&15), row = w*16 + (lane>>4)*4 + reg
    const int cbase = lane & 15;
    const int er4 = w * 16 + g * 4;
    float bias[8];
    #pragma unroll
    for (int ct = 0; ct < 8; ++ct) bias[ct] = bm[ct * 16 + cbase];

    int cur = dsh[er4];
    float sum[8];
    #pragma unroll
    for (int ct = 0; ct < 8; ++ct) sum[ct] = fmaxf(acc[ct][0] + bias[ct], 0.f);
    #pragma unroll
    for (int reg = 1; reg < 4; ++reg) {
        const int d = dsh[er4 + reg];
        if (d == cur) {
            #pragma unroll
            for (int ct = 0; ct < 8; ++ct)
                sum[ct] += fmaxf(acc[ct][reg] + bias[ct], 0.f);
        } else {
            float* ap = &agg[(size_t)cur * ZD + cbase];
            #pragma unroll
            for (int ct = 0; ct < 8; ++ct) atomicAdd(ap + ct * 16, sum[ct]);
            cur = d;
            #pragma unroll
            for (int ct = 0; ct < 8; ++ct) sum[ct] = fmaxf(acc[ct][reg] + bias[ct], 0.f);
        }
    }
    float* ap = &agg[(size_t)cur * ZD + cbase];
    #pragma unroll
    for (int ct = 0; ct < 8; ++ct) atomicAdd(ap + ct * 16, sum[ct]);
}

// ---------------- node MLP (validated R5) ----------------

template<int DIN>
__global__ __launch_bounds__(256, 4) void node_mlp(
    const float* __restrict__ xin,
    const float* __restrict__ agg,
    const int* __restrict__ deg,
    const float* __restrict__ Wf,
    const float* __restrict__ bf,
    float* __restrict__ xout)
{
    constexpr int LDW = ZD + 8;
    __shared__ float fs[64][LDW];
    const int t  = threadIdx.x;
    const int n0 = blockIdx.x * 64;
    const int zc = (t & 31) * 4;
    const int er = (t >> 5) * 8;
    float acc[8][4] = {};

    {
        constexpr int TPR = DIN / 4;
        constexpr int RPI = 256 / TPR;
        const int lk = (t % TPR) * 4;
        for (int r = t / TPR; r < 64; r += RPI) {
            const int n = n0 + r;
            float4 v = make_float4(0.f, 0.f, 0.f, 0.f);
            if (n < NN) v = *(const float4*)&xin[(size_t)n * DIN + lk];
            *(float4*)&fs[r][lk] = v;
        }
        __syncthreads();
        gemm_acc<LDW>(fs, Wf, DIN, zc, er, acc);
        __syncthreads();
    }
    {
        const int lk = (t & 31) * 4;
        for (int r = t >> 5; r < 64; r += 8) {
            const int n = n0 + r;
            float4 v = make_float4(0.f, 0.f, 0.f, 0.f);
            if (n < NN) {
                const float inv = 1.0f / fmaxf((float)deg[n], 1.0f);
                const float4 a = *(const float4*)&agg[(size_t)n * ZD + lk];
                v = make_float4(a.x * inv, a.y * inv, a.z * inv, a.w * inv);
            }
            *(float4*)&fs[r][lk] = v;
        }
        __syncthreads();
        gemm_acc<LDW>(fs, Wf + (size_t)DIN * ZD, ZD, zc, er, acc);
        __syncthreads();
    }

    const float4 b = *(const float4*)&bf[zc];
    #pragma unroll
    for (int i = 0; i < 8; ++i) {
        const int n = n0 + er + i;
        if (n < NN) {
            float4 o;
            o.x = fmaxf(acc[i][0] + b.x, 0.f);
            o.y = fmaxf(acc[i][1] + b.y, 0.f);
            o.z = fmaxf(acc[i][2] + b.z, 0.f);
            o.w = fmaxf(acc[i][3] + b.w, 0.f);
            *(float4*)&xout[(size_t)n * ZD + zc] = o;
        }
    }
}

// ---------------- fusion (validated R5) ----------------

__global__ __launch_bounds__(256, 4) void fusion_kernel(
    const float* __restrict__ x1,
    const float* __restrict__ x2,
    const float* __restrict__ x3,
    const float* __restrict__ Wl,
    const float* __restrict__ bl,
    float* __restrict__ out)
{
    constexpr int LDW = ZD + 8;
    __shared__ float fs[64][LDW];
    const int t  = threadIdx.x;
    const int n0 = blockIdx.x * 64;
    const int zc = (t & 31) * 4;
    const int er = (t >> 5) * 8;
    float acc[8][4] = {};
    const float* srcs[3] = {x1, x2, x3};

    for (int s = 0; s < 3; ++s) {
        const float* xs = srcs[s];
        const int lk = (t & 31) * 4;
        for (int r = t >> 5; r < 64; r += 8) {
            const int n = n0 + r;
            float4 v = make_float4(0.f, 0.f, 0.f, 0.f);
            if (n < NN) v = *(const float4*)&xs[(size_t)n * ZD + lk];
            *(float4*)&fs[r][lk] = v;
        }
        __syncthreads();
        gemm_acc<LDW>(fs, Wl + (size_t)(s * ZD) * ZD, ZD, zc, er, acc);
        __syncthreads();
    }

    const float4 b = *(const float4*)&bl[zc];
    #pragma unroll
    for (int i = 0; i < 8; ++i) {
        const int n = n0 + er + i;
        if (n < NN) {
            float4 o;
            o.x = fmaxf(acc[i][0] + b.x, 0.f);
            o.y = fmaxf(acc[i][1] + b.y, 0.f);
            o.z = fmaxf(acc[i][2] + b.z, 0.f);
            o.w = fmaxf(acc[i][3] + b.w, 0.f);
            *(float4*)&out[(size_t)n * ZD + zc] = o;
        }
    }
}

extern "C" void kernel_launch(void* const* d_in, const int* in_sizes, int n_in,
                              void* d_out, int out_size, void* d_ws, size_t ws_size,
                              hipStream_t stream)
{
    (void)in_sizes; (void)n_in; (void)out_size; (void)ws_size;

    const float* x   = (const float*)d_in[0];
    const int*   ei  = (const int*)d_in[1];
    const float* ea  = (const float*)d_in[2];
    const float* Wm1 = (const float*)d_in[3];  const float* bm1 = (const float*)d_in[4];
    const float* Wf1 = (const float*)d_in[5];  const float* bf1 = (const float*)d_in[6];
    const float* Wm2 = (const float*)d_in[7];  const float* bm2 = (const float*)d_in[8];
    const float* Wf2 = (const float*)d_in[9];  const float* bf2 = (const float*)d_in[10];
    const float* Wm3 = (const float*)d_in[11]; const float* bm3 = (const float*)d_in[12];
    const float* Wf3 = (const float*)d_in[13]; const float* bf3 = (const float*)d_in[14];
    const float* Wl  = (const float*)d_in[15]; const float* bl  = (const float*)d_in[16];

    const int* src = ei;
    const int* dst = ei + NE;

    // ws layout (floats/ints then packed weights; ~35.3 MB):
    float* agg  = (float*)d_ws;
    float* x1   = agg + (size_t)NN * ZD;
    float* x2   = x1  + (size_t)NN * ZD;
    int*   hist = (int*)(x2 + (size_t)NN * ZD);
    int*   curs = hist + 20480;
    int*   src_s = curs + 20480;
    int*   dst_s = src_s + NE;
    int*   perm  = dst_s + NE;
    // packed weights: conv1 Kpad=224 (7 ks), conv2/3 Kpad=416 (13 ks); frag-lanes = ks*512
    const int F1 = 7 * 512, F2 = 13 * 512;
    unsigned short* B1h = (unsigned short*)(perm + NE);
    unsigned short* B1l = B1h + (size_t)F1 * 8;
    unsigned short* B2h = B1l + (size_t)F1 * 8;
    unsigned short* B2l = B2h + (size_t)F2 * 8;
    unsigned short* B3h = B2l + (size_t)F2 * 8;
    unsigned short* B3l = B3h + (size_t)F2 * 8;
    float* x3   = (float*)d_out;
    float* out  = (float*)d_out;

    const size_t aggBytes = (size_t)NN * ZD * sizeof(float);

    // ---- counting sort by dst + weight packing ----
    hipMemsetAsync(hist, 0, 20480 * sizeof(int), stream);
    hist_kernel<<<(NE + 255) / 256, 256, 0, stream>>>(dst, hist);
    scan_kernel<<<1, 1024, 0, stream>>>(hist, curs);
    scatter_kernel<<<(NE + 255) / 256, 256, 0, stream>>>(src, dst, curs, src_s, dst_s, perm);
    pack_w<<<(F1 + 255) / 256, 256, 0, stream>>>(Wm1, 196, F1, B1h, B1l);
    pack_w<<<(F2 + 255) / 256, 256, 0, stream>>>(Wm2, 388, F2, B2h, B2l);
    pack_w<<<(F2 + 255) / 256, 256, 0, stream>>>(Wm3, 388, F2, B3h, B3l);

    const int EG = NE / 64;
    const int NG = (NN + 63) / 64;

    // conv1
    hipMemsetAsync(agg, 0, aggBytes, stream);
    edge_msg_mfma<64><<<EG, 256, 0, stream>>>(x, src_s, dst_s, perm, (const float4*)ea,
                                              B1h, B1l, bm1, agg);
    node_mlp<64><<<NG, 256, 0, stream>>>(x, agg, hist, Wf1, bf1, x1);

    // conv2
    hipMemsetAsync(agg, 0, aggBytes, stream);
    edge_msg_mfma<128><<<EG, 256, 0, stream>>>(x1, src_s, dst_s, perm, (const float4*)ea,
                                               B2h, B2l, bm2, agg);
    node_mlp<128><<<NG, 256, 0, stream>>>(x1, agg, hist, Wf2, bf2, x2);

    // conv3
    hipMemsetAsync(agg, 0, aggBytes, stream);
    edge_msg_mfma<128><<<EG, 256, 0, stream>>>(x2, src_s, dst_s, perm, (const float4*)ea,
                                               B3h, B3l, bm3, agg);
    node_mlp<128><<<NG, 256, 0, stream>>>(x2, agg, hist, Wf3, bf3, x3);

    // fusion
    fusion_kernel<<<NG, 256, 0, stream>>>(x1, x2, x3, Wl, bl, out);
}

// Round 7
// 692.221 us; speedup vs baseline: 3.1213x; 1.4872x over previous
//
#include <hip/hip_runtime.h>

#define NN 20000
#define NE 320000
#define ZD 128

typedef __attribute__((ext_vector_type(8))) short s16x8;
typedef __attribute__((ext_vector_type(16))) float f32x16;

#define MFMA32(A, B, C) __builtin_amdgcn_mfma_f32_32x32x16_bf16((A), (B), (C), 0, 0, 0)

__device__ __forceinline__ unsigned short bf16_rne(float v) {
    unsigned int u = __float_as_uint(v);
    unsigned int r = u + 0x7FFFu + ((u >> 16) & 1u);
    return (unsigned short)(r >> 16);
}
__device__ __forceinline__ float bf16f(unsigned short h) {
    return __uint_as_float(((unsigned int)h) << 16);
}

// ---------------- fp32 LDS-tile GEMM helper (node_mlp / fusion, validated) ----------------

#define ACC_STEP(A, W) \
    acc[i][0] = fmaf((A), (W).x, acc[i][0]); \
    acc[i][1] = fmaf((A), (W).y, acc[i][1]); \
    acc[i][2] = fmaf((A), (W).z, acc[i][2]); \
    acc[i][3] = fmaf((A), (W).w, acc[i][3]);

template<int LDW>
__device__ __forceinline__ void gemm_acc(const float (&fs)[64][LDW],
                                         const float* __restrict__ W,
                                         int SW, int zc, int er,
                                         float (&acc)[8][4])
{
    #pragma unroll 2
    for (int k = 0; k < SW; k += 4) {
        const float* wr = W + (size_t)k * ZD + zc;
        const float4 w0 = *(const float4*)(wr);
        const float4 w1 = *(const float4*)(wr + ZD);
        const float4 w2 = *(const float4*)(wr + 2 * ZD);
        const float4 w3 = *(const float4*)(wr + 3 * ZD);
        #pragma unroll
        for (int i = 0; i < 8; ++i) {
            const float4 a = *(const float4*)&fs[er + i][k];
            ACC_STEP(a.x, w0)
            ACC_STEP(a.y, w1)
            ACC_STEP(a.z, w2)
            ACC_STEP(a.w, w3)
        }
    }
}

// ---------------- counting sort by dst (validated R5) ----------------

__global__ __launch_bounds__(256) void hist_kernel(const int* __restrict__ dst,
                                                   int* __restrict__ hist)
{
    const int e = blockIdx.x * 256 + threadIdx.x;
    if (e < NE) atomicAdd(&hist[dst[e]], 1);
}

__global__ __launch_bounds__(1024) void scan_kernel(const int* __restrict__ hist,
                                                    int* __restrict__ curs)
{
    __shared__ int tmp[1024];
    __shared__ int carry;
    const int t = threadIdx.x;
    if (t == 0) carry = 0;
    __syncthreads();
    for (int base = 0; base < NN; base += 1024) {
        const int i = base + t;
        const int v = (i < NN) ? hist[i] : 0;
        tmp[t] = v;
        __syncthreads();
        for (int off = 1; off < 1024; off <<= 1) {
            const int u = (t >= off) ? tmp[t - off] : 0;
            __syncthreads();
            tmp[t] += u;
            __syncthreads();
        }
        const int incl = tmp[t];
        if (i < NN) curs[i] = carry + incl - v;
        __syncthreads();
        if (t == 1023) carry += incl;
        __syncthreads();
    }
}

__global__ __launch_bounds__(256) void scatter_kernel(
    const int* __restrict__ src, const int* __restrict__ dst,
    int* __restrict__ curs,
    int* __restrict__ src_s, int* __restrict__ dst_s, int* __restrict__ perm)
{
    const int e = blockIdx.x * 256 + threadIdx.x;
    if (e < NE) {
        const int d = dst[e];
        const int p = atomicAdd(&curs[d], 1);
        src_s[p] = src[e];
        dst_s[p] = d;
        perm[p] = e;
    }
}

// ---------------- weight packing: 32x32x16 B-fragment order (hi/lo bf16) ----------------
// frag f = (ks*4 + ct)*64 + lane; lane holds B[k = ks*16 + (lane>>5)*8 + i][col = ct*32 + (lane&31)]

__global__ __launch_bounds__(256) void pack_w(const float* __restrict__ W, int K, int total,
                                              unsigned short* __restrict__ Bh,
                                              unsigned short* __restrict__ Bl)
{
    const int f = blockIdx.x * 256 + threadIdx.x;
    if (f >= total) return;
    const int lane = f & 63;
    const int ct = (f >> 6) & 3;
    const int ks = f >> 8;
    const int k0 = ks * 16 + (lane >> 5) * 8;
    const int col = ct * 32 + (lane & 31);
    unsigned short* oh = Bh + (size_t)f * 8;
    unsigned short* ol = Bl + (size_t)f * 8;
    #pragma unroll
    for (int i = 0; i < 8; ++i) {
        const int k = k0 + i;
        const float v = (k < K) ? W[(size_t)k * ZD + col] : 0.f;
        const unsigned short h = bf16_rne(v);
        oh[i] = h;
        ol[i] = bf16_rne(v - bf16f(h));
    }
}

// ---------------- MFMA 32x32x16 split-bf16 message GEMM + run-reduced scatter ----------------
// Block: 64 sorted edges x 128 cols. 4 waves; wave w owns col-tile w (32 cols) x both 32-row tiles.
// A staged per 64-col slab in LDS (hi/lo bf16) with XOR swizzle byte^=((row&7)<<4).

template<int DIN>
__global__ __launch_bounds__(256, 4) void edge_msg_mfma(
    const float* __restrict__ x,
    const int* __restrict__ src_s,
    const int* __restrict__ dst_s,   // sorted
    const int* __restrict__ perm,
    const float4* __restrict__ ea,
    const unsigned short* __restrict__ Bh,
    const unsigned short* __restrict__ Bl,
    const float* __restrict__ bm,
    float* __restrict__ agg)
{
    constexpr int NSLAB = 3 * DIN / 64;
    __shared__ unsigned short fsh[64][64];   // 8 KB (row = 128 B)
    __shared__ unsigned short fsl[64][64];
    __shared__ int dsh[64];
    const int t = threadIdx.x;
    const int e0 = blockIdx.x * 64;
    const int lane = t & 63;
    const int w = t >> 6;

    f32x16 acc0 = {0,0,0,0,0,0,0,0,0,0,0,0,0,0,0,0};
    f32x16 acc1 = {0,0,0,0,0,0,0,0,0,0,0,0,0,0,0,0};

    if (t < 64) dsh[t] = dst_s[e0 + t];

    const int cl = lane & 31;
    const int g2 = lane >> 5;                // k-octet
    const int ar0 = cl;                      // row-tile 0 A-row
    const int ar1 = 32 + cl;                 // row-tile 1 A-row
    char* const fshB = (char*)fsh;
    char* const fslB = (char*)fsl;

    const int sc = (t & 15) * 8;             // staging byte-col (uint2 = 4 shorts)
    const int sr0 = t >> 4;

    for (int s = 0; s < NSLAB; ++s) {
        const int kind = (s * 64) / DIN;
        const int col0 = (s * 64) % DIN;
        // ---- stage 64x64 slab as hi/lo bf16, swizzled ----
        #pragma unroll
        for (int p = 0; p < 4; ++p) {
            const int r = sr0 + p * 16;
            const int e = e0 + r;
            float4 v;
            if (kind == 0) {
                v = *(const float4*)&x[(size_t)dst_s[e] * DIN + col0 + sc / 2];
            } else {
                const float4 xi = *(const float4*)&x[(size_t)dst_s[e] * DIN + col0 + sc / 2];
                const float4 xj = *(const float4*)&x[(size_t)src_s[e] * DIN + col0 + sc / 2];
                if (kind == 1) v = make_float4(xj.x - xi.x, xj.y - xi.y, xj.z - xi.z, xj.w - xi.w);
                else           v = make_float4(xj.x * xi.x, xj.y * xi.y, xj.z * xi.z, xj.w * xi.w);
            }
            const float vv[4] = {v.x, v.y, v.z, v.w};
            unsigned int hp[2], lp[2];
            #pragma unroll
            for (int q = 0; q < 2; ++q) {
                const unsigned short h0 = bf16_rne(vv[2*q]);
                const unsigned short h1 = bf16_rne(vv[2*q+1]);
                const unsigned short l0 = bf16_rne(vv[2*q]   - bf16f(h0));
                const unsigned short l1 = bf16_rne(vv[2*q+1] - bf16f(h1));
                hp[q] = (unsigned int)h0 | ((unsigned int)h1 << 16);
                lp[q] = (unsigned int)l0 | ((unsigned int)l1 << 16);
            }
            const int off = r * 128 + (sc ^ ((r & 7) << 4));
            *(uint2*)(fshB + off) = make_uint2(hp[0], hp[1]);
            *(uint2*)(fslB + off) = make_uint2(lp[0], lp[1]);
        }
        __syncthreads();
        // ---- 4 K-steps of 16 ----
        #pragma unroll
        for (int kl = 0; kl < 4; ++kl) {
            const int ks = s * 4 + kl;
            const int kb = kl * 32 + g2 * 16;
            const s16x8 ah0 = *(const s16x8*)(fshB + ar0 * 128 + (kb ^ ((ar0 & 7) << 4)));
            const s16x8 al0 = *(const s16x8*)(fslB + ar0 * 128 + (kb ^ ((ar0 & 7) << 4)));
            const s16x8 ah1 = *(const s16x8*)(fshB + ar1 * 128 + (kb ^ ((ar1 & 7) << 4)));
            const s16x8 al1 = *(const s16x8*)(fslB + ar1 * 128 + (kb ^ ((ar1 & 7) << 4)));
            const unsigned short* bp = Bh + ((size_t)(ks * 4 + w) * 64 + lane) * 8;
            const unsigned short* lp = Bl + ((size_t)(ks * 4 + w) * 64 + lane) * 8;
            const s16x8 bh = *(const s16x8*)bp;
            const s16x8 bl = *(const s16x8*)lp;
            acc0 = MFMA32(al0, bh, acc0);
            acc0 = MFMA32(ah0, bl, acc0);
            acc0 = MFMA32(ah0, bh, acc0);
            acc1 = MFMA32(al1, bh, acc1);
            acc1 = MFMA32(ah1, bl, acc1);
            acc1 = MFMA32(ah1, bh, acc1);
        }
        __syncthreads();
    }

    // ---- tail: ea slab (32 k-cols: 4 real + 28 zero), 2 K-steps ----
    {
        const int r = t >> 2, cblk = t & 3;
        unsigned int hw[4] = {0, 0, 0, 0}, lw[4] = {0, 0, 0, 0};
        if (cblk == 0) {
            const float4 a = ea[perm[e0 + r]];
            const float vv[4] = {a.x, a.y, a.z, a.w};
            #pragma unroll
            for (int q = 0; q < 2; ++q) {
                const unsigned short h0 = bf16_rne(vv[2*q]);
                const unsigned short h1 = bf16_rne(vv[2*q+1]);
                const unsigned short l0 = bf16_rne(vv[2*q]   - bf16f(h0));
                const unsigned short l1 = bf16_rne(vv[2*q+1] - bf16f(h1));
                hw[q] = (unsigned int)h0 | ((unsigned int)h1 << 16);
                lw[q] = (unsigned int)l0 | ((unsigned int)l1 << 16);
            }
        }
        const int off = r * 128 + ((cblk * 16) ^ ((r & 7) << 4));
        *(uint4*)(fshB + off) = make_uint4(hw[0], hw[1], hw[2], hw[3]);
        *(uint4*)(fslB + off) = make_uint4(lw[0], lw[1], lw[2], lw[3]);
        __syncthreads();
        #pragma unroll
        for (int kl = 0; kl < 2; ++kl) {
            const int ks = NSLAB * 4 + kl;
            const int kb = kl * 32 + g2 * 16;
            const s16x8 ah0 = *(const s16x8*)(fshB + ar0 * 128 + (kb ^ ((ar0 & 7) << 4)));
            const s16x8 al0 = *(const s16x8*)(fslB + ar0 * 128 + (kb ^ ((ar0 & 7) << 4)));
            const s16x8 ah1 = *(const s16x8*)(fshB + ar1 * 128 + (kb ^ ((ar1 & 7) << 4)));
            const s16x8 al1 = *(const s16x8*)(fslB + ar1 * 128 + (kb ^ ((ar1 & 7) << 4)));
            const unsigned short* bp = Bh + ((size_t)(ks * 4 + w) * 64 + lane) * 8;
            const unsigned short* lp2 = Bl + ((size_t)(ks * 4 + w) * 64 + lane) * 8;
            const s16x8 bh = *(const s16x8*)bp;
            const s16x8 bl = *(const s16x8*)lp2;
            acc0 = MFMA32(al0, bh, acc0);
            acc0 = MFMA32(ah0, bl, acc0);
            acc0 = MFMA32(ah0, bh, acc0);
            acc1 = MFMA32(al1, bh, acc1);
            acc1 = MFMA32(ah1, bl, acc1);
            acc1 = MFMA32(ah1, bh, acc1);
        }
    }

    // ---- bias + relu + run-reduced atomic scatter ----
    // C/D: col = ct*32 + (lane&31); row = rt*32 + (reg&3) + 8*(reg>>2) + 4*(lane>>5)
    const int col = w * 32 + cl;
    const float bias = bm[col];
    int cur = -1;
    float sum = 0.f;
    #pragma unroll
    for (int rt = 0; rt < 2; ++rt) {
        #pragma unroll
        for (int reg = 0; reg < 16; ++reg) {
            const int row = rt * 32 + (reg & 3) + 8 * (reg >> 2) + 4 * g2;
            const float v = fmaxf((rt == 0 ? acc0[reg] : acc1[reg]) + bias, 0.f);
            const int d = dsh[row];
            if (d == cur) {
                sum += v;
            } else {
                if (cur >= 0) atomicAdd(&agg[(size_t)cur * ZD + col], sum);
                cur = d;
                sum = v;
            }
        }
    }
    atomicAdd(&agg[(size_t)cur * ZD + col], sum);
}

// ---------------- node MLP (validated R5) ----------------

template<int DIN>
__global__ __launch_bounds__(256, 4) void node_mlp(
    const float* __restrict__ xin,
    const float* __restrict__ agg,
    const int* __restrict__ deg,
    const float* __restrict__ Wf,
    const float* __restrict__ bf,
    float* __restrict__ xout)
{
    constexpr int LDW = ZD + 8;
    __shared__ float fs[64][LDW];
    const int t  = threadIdx.x;
    const int n0 = blockIdx.x * 64;
    const int zc = (t & 31) * 4;
    const int er = (t >> 5) * 8;
    float acc[8][4] = {};

    {
        constexpr int TPR = DIN / 4;
        constexpr int RPI = 256 / TPR;
        const int lk = (t % TPR) * 4;
        for (int r = t / TPR; r < 64; r += RPI) {
            const int n = n0 + r;
            float4 v = make_float4(0.f, 0.f, 0.f, 0.f);
            if (n < NN) v = *(const float4*)&xin[(size_t)n * DIN + lk];
            *(float4*)&fs[r][lk] = v;
        }
        __syncthreads();
        gemm_acc<LDW>(fs, Wf, DIN, zc, er, acc);
        __syncthreads();
    }
    {
        const int lk = (t & 31) * 4;
        for (int r = t >> 5; r < 64; r += 8) {
            const int n = n0 + r;
            float4 v = make_float4(0.f, 0.f, 0.f, 0.f);
            if (n < NN) {
                const float inv = 1.0f / fmaxf((float)deg[n], 1.0f);
                const float4 a = *(const float4*)&agg[(size_t)n * ZD + lk];
                v = make_float4(a.x * inv, a.y * inv, a.z * inv, a.w * inv);
            }
            *(float4*)&fs[r][lk] = v;
        }
        __syncthreads();
        gemm_acc<LDW>(fs, Wf + (size_t)DIN * ZD, ZD, zc, er, acc);
        __syncthreads();
    }

    const float4 b = *(const float4*)&bf[zc];
    #pragma unroll
    for (int i = 0; i < 8; ++i) {
        const int n = n0 + er + i;
        if (n < NN) {
            float4 o;
            o.x = fmaxf(acc[i][0] + b.x, 0.f);
            o.y = fmaxf(acc[i][1] + b.y, 0.f);
            o.z = fmaxf(acc[i][2] + b.z, 0.f);
            o.w = fmaxf(acc[i][3] + b.w, 0.f);
            *(float4*)&xout[(size_t)n * ZD + zc] = o;
        }
    }
}

// ---------------- fusion (validated R5) ----------------

__global__ __launch_bounds__(256, 4) void fusion_kernel(
    const float* __restrict__ x1,
    const float* __restrict__ x2,
    const float* __restrict__ x3,
    const float* __restrict__ Wl,
    const float* __restrict__ bl,
    float* __restrict__ out)
{
    constexpr int LDW = ZD + 8;
    __shared__ float fs[64][LDW];
    const int t  = threadIdx.x;
    const int n0 = blockIdx.x * 64;
    const int zc = (t & 31) * 4;
    const int er = (t >> 5) * 8;
    float acc[8][4] = {};
    const float* srcs[3] = {x1, x2, x3};

    for (int s = 0; s < 3; ++s) {
        const float* xs = srcs[s];
        const int lk = (t & 31) * 4;
        for (int r = t >> 5; r < 64; r += 8) {
            const int n = n0 + r;
            float4 v = make_float4(0.f, 0.f, 0.f, 0.f);
            if (n < NN) v = *(const float4*)&xs[(size_t)n * ZD + lk];
            *(float4*)&fs[r][lk] = v;
        }
        __syncthreads();
        gemm_acc<LDW>(fs, Wl + (size_t)(s * ZD) * ZD, ZD, zc, er, acc);
        __syncthreads();
    }

    const float4 b = *(const float4*)&bl[zc];
    #pragma unroll
    for (int i = 0; i < 8; ++i) {
        const int n = n0 + er + i;
        if (n < NN) {
            float4 o;
            o.x = fmaxf(acc[i][0] + b.x, 0.f);
            o.y = fmaxf(acc[i][1] + b.y, 0.f);
            o.z = fmaxf(acc[i][2] + b.z, 0.f);
            o.w = fmaxf(acc[i][3] + b.w, 0.f);
            *(float4*)&out[(size_t)n * ZD + zc] = o;
        }
    }
}

extern "C" void kernel_launch(void* const* d_in, const int* in_sizes, int n_in,
                              void* d_out, int out_size, void* d_ws, size_t ws_size,
                              hipStream_t stream)
{
    (void)in_sizes; (void)n_in; (void)out_size; (void)ws_size;

    const float* x   = (const float*)d_in[0];
    const int*   ei  = (const int*)d_in[1];
    const float* ea  = (const float*)d_in[2];
    const float* Wm1 = (const float*)d_in[3];  const float* bm1 = (const float*)d_in[4];
    const float* Wf1 = (const float*)d_in[5];  const float* bf1 = (const float*)d_in[6];
    const float* Wm2 = (const float*)d_in[7];  const float* bm2 = (const float*)d_in[8];
    const float* Wf2 = (const float*)d_in[9];  const float* bf2 = (const float*)d_in[10];
    const float* Wm3 = (const float*)d_in[11]; const float* bm3 = (const float*)d_in[12];
    const float* Wf3 = (const float*)d_in[13]; const float* bf3 = (const float*)d_in[14];
    const float* Wl  = (const float*)d_in[15]; const float* bl  = (const float*)d_in[16];

    const int* src = ei;
    const int* dst = ei + NE;

    float* agg  = (float*)d_ws;
    float* x1   = agg + (size_t)NN * ZD;
    float* x2   = x1  + (size_t)NN * ZD;
    int*   hist = (int*)(x2 + (size_t)NN * ZD);
    int*   curs = hist + 20480;
    int*   src_s = curs + 20480;
    int*   dst_s = src_s + NE;
    int*   perm  = dst_s + NE;
    // packed weights (32x32x16): conv1 ksteps=14, conv2/3 ksteps=26; frags = ks*4*64
    const int F1 = 14 * 4 * 64, F2 = 26 * 4 * 64;
    unsigned short* B1h = (unsigned short*)(perm + NE);
    unsigned short* B1l = B1h + (size_t)F1 * 8;
    unsigned short* B2h = B1l + (size_t)F1 * 8;
    unsigned short* B2l = B2h + (size_t)F2 * 8;
    unsigned short* B3h = B2l + (size_t)F2 * 8;
    unsigned short* B3l = B3h + (size_t)F2 * 8;
    float* x3   = (float*)d_out;
    float* out  = (float*)d_out;

    const size_t aggBytes = (size_t)NN * ZD * sizeof(float);

    hipMemsetAsync(hist, 0, 20480 * sizeof(int), stream);
    hist_kernel<<<(NE + 255) / 256, 256, 0, stream>>>(dst, hist);
    scan_kernel<<<1, 1024, 0, stream>>>(hist, curs);
    scatter_kernel<<<(NE + 255) / 256, 256, 0, stream>>>(src, dst, curs, src_s, dst_s, perm);
    pack_w<<<(F1 + 255) / 256, 256, 0, stream>>>(Wm1, 196, F1, B1h, B1l);
    pack_w<<<(F2 + 255) / 256, 256, 0, stream>>>(Wm2, 388, F2, B2h, B2l);
    pack_w<<<(F2 + 255) / 256, 256, 0, stream>>>(Wm3, 388, F2, B3h, B3l);

    const int EG = NE / 64;
    const int NG = (NN + 63) / 64;

    // conv1
    hipMemsetAsync(agg, 0, aggBytes, stream);
    edge_msg_mfma<64><<<EG, 256, 0, stream>>>(x, src_s, dst_s, perm, (const float4*)ea,
                                              B1h, B1l, bm1, agg);
    node_mlp<64><<<NG, 256, 0, stream>>>(x, agg, hist, Wf1, bf1, x1);

    // conv2
    hipMemsetAsync(agg, 0, aggBytes, stream);
    edge_msg_mfma<128><<<EG, 256, 0, stream>>>(x1, src_s, dst_s, perm, (const float4*)ea,
                                               B2h, B2l, bm2, agg);
    node_mlp<128><<<NG, 256, 0, stream>>>(x1, agg, hist, Wf2, bf2, x2);

    // conv3
    hipMemsetAsync(agg, 0, aggBytes, stream);
    edge_msg_mfma<128><<<EG, 256, 0, stream>>>(x2, src_s, dst_s, perm, (const float4*)ea,
                                               B3h, B3l, bm3, agg);
    node_mlp<128><<<NG, 256, 0, stream>>>(x2, agg, hist, Wf3, bf3, x3);

    // fusion
    fusion_kernel<<<NG, 256, 0, stream>>>(x1, x2, x3, Wl, bl, out);
}

// Round 8
// 660.951 us; speedup vs baseline: 3.2689x; 1.0473x over previous
//
#include <hip/hip_runtime.h>

#define NN 20000
#define NE 320000
#define ZD 128

typedef __attribute__((ext_vector_type(8))) short s16x8;
typedef __attribute__((ext_vector_type(16))) float f32x16;

#define MFMA32(A, B, C) __builtin_amdgcn_mfma_f32_32x32x16_bf16((A), (B), (C), 0, 0, 0)

__device__ __forceinline__ unsigned short bf16_rne(float v) {
    unsigned int u = __float_as_uint(v);
    unsigned int r = u + 0x7FFFu + ((u >> 16) & 1u);
    return (unsigned short)(r >> 16);
}
__device__ __forceinline__ float bf16f(unsigned short h) {
    return __uint_as_float(((unsigned int)h) << 16);
}

// ---------------- counting sort by dst (validated R5) ----------------

__global__ __launch_bounds__(256) void hist_kernel(const int* __restrict__ dst,
                                                   int* __restrict__ hist)
{
    const int e = blockIdx.x * 256 + threadIdx.x;
    if (e < NE) atomicAdd(&hist[dst[e]], 1);
}

__global__ __launch_bounds__(1024) void scan_kernel(const int* __restrict__ hist,
                                                    int* __restrict__ curs)
{
    __shared__ int tmp[1024];
    __shared__ int carry;
    const int t = threadIdx.x;
    if (t == 0) carry = 0;
    __syncthreads();
    for (int base = 0; base < NN; base += 1024) {
        const int i = base + t;
        const int v = (i < NN) ? hist[i] : 0;
        tmp[t] = v;
        __syncthreads();
        for (int off = 1; off < 1024; off <<= 1) {
            const int u = (t >= off) ? tmp[t - off] : 0;
            __syncthreads();
            tmp[t] += u;
            __syncthreads();
        }
        const int incl = tmp[t];
        if (i < NN) curs[i] = carry + incl - v;
        __syncthreads();
        if (t == 1023) carry += incl;
        __syncthreads();
    }
}

__global__ __launch_bounds__(256) void scatter_kernel(
    const int* __restrict__ src, const int* __restrict__ dst,
    int* __restrict__ curs,
    int* __restrict__ src_s, int* __restrict__ dst_s, int* __restrict__ perm)
{
    const int e = blockIdx.x * 256 + threadIdx.x;
    if (e < NE) {
        const int d = dst[e];
        const int p = atomicAdd(&curs[d], 1);
        src_s[p] = src[e];
        dst_s[p] = d;
        perm[p] = e;
    }
}

// ---------------- weight packing: 32x32x16 B-fragment order (validated R7) ----------------

__global__ __launch_bounds__(256) void pack_w(const float* __restrict__ W, int K, int total,
                                              unsigned short* __restrict__ Bh,
                                              unsigned short* __restrict__ Bl)
{
    const int f = blockIdx.x * 256 + threadIdx.x;
    if (f >= total) return;
    const int lane = f & 63;
    const int ct = (f >> 6) & 3;
    const int ks = f >> 8;
    const int k0 = ks * 16 + (lane >> 5) * 8;
    const int col = ct * 32 + (lane & 31);
    unsigned short* oh = Bh + (size_t)f * 8;
    unsigned short* ol = Bl + (size_t)f * 8;
    #pragma unroll
    for (int i = 0; i < 8; ++i) {
        const int k = k0 + i;
        const float v = (k < K) ? W[(size_t)k * ZD + col] : 0.f;
        const unsigned short h = bf16_rne(v);
        oh[i] = h;
        ol[i] = bf16_rne(v - bf16f(h));
    }
}

// ---------------- MFMA 32x32x16 split-bf16 message GEMM (validated R7) ----------------

template<int DIN>
__global__ __launch_bounds__(256, 4) void edge_msg_mfma(
    const float* __restrict__ x,
    const int* __restrict__ src_s,
    const int* __restrict__ dst_s,   // sorted
    const int* __restrict__ perm,
    const float4* __restrict__ ea,
    const unsigned short* __restrict__ Bh,
    const unsigned short* __restrict__ Bl,
    const float* __restrict__ bm,
    float* __restrict__ agg)
{
    constexpr int NSLAB = 3 * DIN / 64;
    __shared__ unsigned short fsh[64][64];
    __shared__ unsigned short fsl[64][64];
    __shared__ int dsh[64];
    const int t = threadIdx.x;
    const int e0 = blockIdx.x * 64;
    const int lane = t & 63;
    const int w = t >> 6;

    f32x16 acc0 = {0,0,0,0,0,0,0,0,0,0,0,0,0,0,0,0};
    f32x16 acc1 = {0,0,0,0,0,0,0,0,0,0,0,0,0,0,0,0};

    if (t < 64) dsh[t] = dst_s[e0 + t];

    const int cl = lane & 31;
    const int g2 = lane >> 5;
    const int ar0 = cl;
    const int ar1 = 32 + cl;
    char* const fshB = (char*)fsh;
    char* const fslB = (char*)fsl;

    const int sc = (t & 15) * 8;
    const int sr0 = t >> 4;

    for (int s = 0; s < NSLAB; ++s) {
        const int kind = (s * 64) / DIN;
        const int col0 = (s * 64) % DIN;
        #pragma unroll
        for (int p = 0; p < 4; ++p) {
            const int r = sr0 + p * 16;
            const int e = e0 + r;
            float4 v;
            if (kind == 0) {
                v = *(const float4*)&x[(size_t)dst_s[e] * DIN + col0 + sc / 2];
            } else {
                const float4 xi = *(const float4*)&x[(size_t)dst_s[e] * DIN + col0 + sc / 2];
                const float4 xj = *(const float4*)&x[(size_t)src_s[e] * DIN + col0 + sc / 2];
                if (kind == 1) v = make_float4(xj.x - xi.x, xj.y - xi.y, xj.z - xi.z, xj.w - xi.w);
                else           v = make_float4(xj.x * xi.x, xj.y * xi.y, xj.z * xi.z, xj.w * xi.w);
            }
            const float vv[4] = {v.x, v.y, v.z, v.w};
            unsigned int hp[2], lp[2];
            #pragma unroll
            for (int q = 0; q < 2; ++q) {
                const unsigned short h0 = bf16_rne(vv[2*q]);
                const unsigned short h1 = bf16_rne(vv[2*q+1]);
                const unsigned short l0 = bf16_rne(vv[2*q]   - bf16f(h0));
                const unsigned short l1 = bf16_rne(vv[2*q+1] - bf16f(h1));
                hp[q] = (unsigned int)h0 | ((unsigned int)h1 << 16);
                lp[q] = (unsigned int)l0 | ((unsigned int)l1 << 16);
            }
            const int off = r * 128 + (sc ^ ((r & 7) << 4));
            *(uint2*)(fshB + off) = make_uint2(hp[0], hp[1]);
            *(uint2*)(fslB + off) = make_uint2(lp[0], lp[1]);
        }
        __syncthreads();
        #pragma unroll
        for (int kl = 0; kl < 4; ++kl) {
            const int ks = s * 4 + kl;
            const int kb = kl * 32 + g2 * 16;
            const s16x8 ah0 = *(const s16x8*)(fshB + ar0 * 128 + (kb ^ ((ar0 & 7) << 4)));
            const s16x8 al0 = *(const s16x8*)(fslB + ar0 * 128 + (kb ^ ((ar0 & 7) << 4)));
            const s16x8 ah1 = *(const s16x8*)(fshB + ar1 * 128 + (kb ^ ((ar1 & 7) << 4)));
            const s16x8 al1 = *(const s16x8*)(fslB + ar1 * 128 + (kb ^ ((ar1 & 7) << 4)));
            const unsigned short* bp = Bh + ((size_t)(ks * 4 + w) * 64 + lane) * 8;
            const unsigned short* lp = Bl + ((size_t)(ks * 4 + w) * 64 + lane) * 8;
            const s16x8 bh = *(const s16x8*)bp;
            const s16x8 bl = *(const s16x8*)lp;
            acc0 = MFMA32(al0, bh, acc0);
            acc0 = MFMA32(ah0, bl, acc0);
            acc0 = MFMA32(ah0, bh, acc0);
            acc1 = MFMA32(al1, bh, acc1);
            acc1 = MFMA32(ah1, bl, acc1);
            acc1 = MFMA32(ah1, bh, acc1);
        }
        __syncthreads();
    }

    {   // tail: ea slab (4 real + 28 zero k), 2 K-steps
        const int r = t >> 2, cblk = t & 3;
        unsigned int hw[4] = {0, 0, 0, 0}, lw[4] = {0, 0, 0, 0};
        if (cblk == 0) {
            const float4 a = ea[perm[e0 + r]];
            const float vv[4] = {a.x, a.y, a.z, a.w};
            #pragma unroll
            for (int q = 0; q < 2; ++q) {
                const unsigned short h0 = bf16_rne(vv[2*q]);
                const unsigned short h1 = bf16_rne(vv[2*q+1]);
                const unsigned short l0 = bf16_rne(vv[2*q]   - bf16f(h0));
                const unsigned short l1 = bf16_rne(vv[2*q+1] - bf16f(h1));
                hw[q] = (unsigned int)h0 | ((unsigned int)h1 << 16);
                lw[q] = (unsigned int)l0 | ((unsigned int)l1 << 16);
            }
        }
        const int off = r * 128 + ((cblk * 16) ^ ((r & 7) << 4));
        *(uint4*)(fshB + off) = make_uint4(hw[0], hw[1], hw[2], hw[3]);
        *(uint4*)(fslB + off) = make_uint4(lw[0], lw[1], lw[2], lw[3]);
        __syncthreads();
        #pragma unroll
        for (int kl = 0; kl < 2; ++kl) {
            const int ks = NSLAB * 4 + kl;
            const int kb = kl * 32 + g2 * 16;
            const s16x8 ah0 = *(const s16x8*)(fshB + ar0 * 128 + (kb ^ ((ar0 & 7) << 4)));
            const s16x8 al0 = *(const s16x8*)(fslB + ar0 * 128 + (kb ^ ((ar0 & 7) << 4)));
            const s16x8 ah1 = *(const s16x8*)(fshB + ar1 * 128 + (kb ^ ((ar1 & 7) << 4)));
            const s16x8 al1 = *(const s16x8*)(fslB + ar1 * 128 + (kb ^ ((ar1 & 7) << 4)));
            const unsigned short* bp = Bh + ((size_t)(ks * 4 + w) * 64 + lane) * 8;
            const unsigned short* lp2 = Bl + ((size_t)(ks * 4 + w) * 64 + lane) * 8;
            const s16x8 bh = *(const s16x8*)bp;
            const s16x8 bl = *(const s16x8*)lp2;
            acc0 = MFMA32(al0, bh, acc0);
            acc0 = MFMA32(ah0, bl, acc0);
            acc0 = MFMA32(ah0, bh, acc0);
            acc1 = MFMA32(al1, bh, acc1);
            acc1 = MFMA32(ah1, bl, acc1);
            acc1 = MFMA32(ah1, bh, acc1);
        }
    }

    const int col = w * 32 + cl;
    const float bias = bm[col];
    int cur = -1;
    float sum = 0.f;
    #pragma unroll
    for (int rt = 0; rt < 2; ++rt) {
        #pragma unroll
        for (int reg = 0; reg < 16; ++reg) {
            const int row = rt * 32 + (reg & 3) + 8 * (reg >> 2) + 4 * g2;
            const float v = fmaxf((rt == 0 ? acc0[reg] : acc1[reg]) + bias, 0.f);
            const int d = dsh[row];
            if (d == cur) {
                sum += v;
            } else {
                if (cur >= 0) atomicAdd(&agg[(size_t)cur * ZD + col], sum);
                cur = d;
                sum = v;
            }
        }
    }
    atomicAdd(&agg[(size_t)cur * ZD + col], sum);
}

// ---------------- fp32 4-row GEMM helper for node-side 32-row tiles ----------------
// fs reads are wave-uniform (broadcast) -> conflict-free; W reads L1/L2-hit.

#define ACC4_STEP(A, W) \
    acc[i][0] = fmaf((A), (W).x, acc[i][0]); \
    acc[i][1] = fmaf((A), (W).y, acc[i][1]); \
    acc[i][2] = fmaf((A), (W).z, acc[i][2]); \
    acc[i][3] = fmaf((A), (W).w, acc[i][3]);

template<int K>
__device__ __forceinline__ void gemm_acc4(const float* __restrict__ fs,  // [32][K]
                                          const float* __restrict__ W,
                                          int zc, int er, float (&acc)[4][4])
{
    #pragma unroll 2
    for (int k = 0; k < K; k += 4) {
        const float* wr = W + (size_t)k * ZD + zc;
        const float4 w0 = *(const float4*)(wr);
        const float4 w1 = *(const float4*)(wr + ZD);
        const float4 w2 = *(const float4*)(wr + 2 * ZD);
        const float4 w3 = *(const float4*)(wr + 3 * ZD);
        #pragma unroll
        for (int i = 0; i < 4; ++i) {
            const float4 a = *(const float4*)&fs[(er + i) * K + k];
            ACC4_STEP(a.x, w0)
            ACC4_STEP(a.y, w1)
            ACC4_STEP(a.z, w2)
            ACC4_STEP(a.w, w3)
        }
    }
}

// ---------------- node MLP: 32-row tiles, single-shot staging ----------------
// out = relu([xin | agg/deg] @ Wf + bf). Grid 625 (20000/32 exact).

template<int DIN>
__global__ __launch_bounds__(256, 4) void node_mlp32(
    const float* __restrict__ xin,
    const float* __restrict__ agg,
    const int* __restrict__ deg,
    const float* __restrict__ Wf,
    const float* __restrict__ bf,
    float* __restrict__ xout)
{
    constexpr int K = DIN + 128;
    __shared__ float fs[32 * K];
    const int t  = threadIdx.x;
    const int n0 = blockIdx.x * 32;

    {   // stage xin slab: 32*DIN/4 float4
        constexpr int CPR = DIN / 4;           // float4 per row
        constexpr int LX = 32 * CPR / 256;     // loads per thread (2 or 4)
        #pragma unroll
        for (int p = 0; p < LX; ++p) {
            const int f = t + 256 * p;
            const int r = f / CPR, c = f % CPR;
            *(float4*)&fs[r * K + c * 4] = *(const float4*)&xin[(size_t)(n0 + r) * DIN + c * 4];
        }
    }
    {   // stage agg/deg slab: 32*32 float4
        #pragma unroll
        for (int p = 0; p < 4; ++p) {
            const int f = t + 256 * p;
            const int r = f >> 5, c = f & 31;
            const float inv = 1.0f / fmaxf((float)deg[n0 + r], 1.0f);
            const float4 a = *(const float4*)&agg[(size_t)(n0 + r) * ZD + c * 4];
            *(float4*)&fs[r * K + DIN + c * 4] =
                make_float4(a.x * inv, a.y * inv, a.z * inv, a.w * inv);
        }
    }
    __syncthreads();

    const int zc = (t & 31) * 4;
    const int er = (t >> 5) * 4;
    float acc[4][4] = {};
    gemm_acc4<K>(fs, Wf, zc, er, acc);

    const float4 b = *(const float4*)&bf[zc];
    #pragma unroll
    for (int i = 0; i < 4; ++i) {
        float4 o;
        o.x = fmaxf(acc[i][0] + b.x, 0.f);
        o.y = fmaxf(acc[i][1] + b.y, 0.f);
        o.z = fmaxf(acc[i][2] + b.z, 0.f);
        o.w = fmaxf(acc[i][3] + b.w, 0.f);
        *(float4*)&xout[(size_t)(n0 + er + i) * ZD + zc] = o;
    }
}

// ---------------- fusion: 32-row tiles, single-shot staging ----------------
// out = relu([x1|x2|x3] @ Wl + bl); x3 == out (in-place safe: own rows only).

__global__ __launch_bounds__(256, 3) void fusion32(
    const float* __restrict__ x1,
    const float* __restrict__ x2,
    const float* __restrict__ x3,
    const float* __restrict__ Wl,
    const float* __restrict__ bl,
    float* __restrict__ out)
{
    constexpr int K = 384;
    __shared__ float fs[32 * K];   // 48 KB
    const int t  = threadIdx.x;
    const int n0 = blockIdx.x * 32;

    #pragma unroll
    for (int p = 0; p < 4; ++p) {
        const int f = t + 256 * p;
        const int r = f >> 5, c = f & 31;
        *(float4*)&fs[r * K + c * 4] = *(const float4*)&x1[(size_t)(n0 + r) * ZD + c * 4];
    }
    #pragma unroll
    for (int p = 0; p < 4; ++p) {
        const int f = t + 256 * p;
        const int r = f >> 5, c = f & 31;
        *(float4*)&fs[r * K + 128 + c * 4] = *(const float4*)&x2[(size_t)(n0 + r) * ZD + c * 4];
    }
    #pragma unroll
    for (int p = 0; p < 4; ++p) {
        const int f = t + 256 * p;
        const int r = f >> 5, c = f & 31;
        *(float4*)&fs[r * K + 256 + c * 4] = *(const float4*)&x3[(size_t)(n0 + r) * ZD + c * 4];
    }
    __syncthreads();

    const int zc = (t & 31) * 4;
    const int er = (t >> 5) * 4;
    float acc[4][4] = {};
    gemm_acc4<K>(fs, Wl, zc, er, acc);

    const float4 b = *(const float4*)&bl[zc];
    #pragma unroll
    for (int i = 0; i < 4; ++i) {
        float4 o;
        o.x = fmaxf(acc[i][0] + b.x, 0.f);
        o.y = fmaxf(acc[i][1] + b.y, 0.f);
        o.z = fmaxf(acc[i][2] + b.z, 0.f);
        o.w = fmaxf(acc[i][3] + b.w, 0.f);
        *(float4*)&out[(size_t)(n0 + er + i) * ZD + zc] = o;
    }
}

extern "C" void kernel_launch(void* const* d_in, const int* in_sizes, int n_in,
                              void* d_out, int out_size, void* d_ws, size_t ws_size,
                              hipStream_t stream)
{
    (void)in_sizes; (void)n_in; (void)out_size; (void)ws_size;

    const float* x   = (const float*)d_in[0];
    const int*   ei  = (const int*)d_in[1];
    const float* ea  = (const float*)d_in[2];
    const float* Wm1 = (const float*)d_in[3];  const float* bm1 = (const float*)d_in[4];
    const float* Wf1 = (const float*)d_in[5];  const float* bf1 = (const float*)d_in[6];
    const float* Wm2 = (const float*)d_in[7];  const float* bm2 = (const float*)d_in[8];
    const float* Wf2 = (const float*)d_in[9];  const float* bf2 = (const float*)d_in[10];
    const float* Wm3 = (const float*)d_in[11]; const float* bm3 = (const float*)d_in[12];
    const float* Wf3 = (const float*)d_in[13]; const float* bf3 = (const float*)d_in[14];
    const float* Wl  = (const float*)d_in[15]; const float* bl  = (const float*)d_in[16];

    const int* src = ei;
    const int* dst = ei + NE;

    float* agg  = (float*)d_ws;
    float* x1   = agg + (size_t)NN * ZD;
    float* x2   = x1  + (size_t)NN * ZD;
    int*   hist = (int*)(x2 + (size_t)NN * ZD);
    int*   curs = hist + 20480;
    int*   src_s = curs + 20480;
    int*   dst_s = src_s + NE;
    int*   perm  = dst_s + NE;
    const int F1 = 14 * 4 * 64, F2 = 26 * 4 * 64;
    unsigned short* B1h = (unsigned short*)(perm + NE);
    unsigned short* B1l = B1h + (size_t)F1 * 8;
    unsigned short* B2h = B1l + (size_t)F1 * 8;
    unsigned short* B2l = B2h + (size_t)F2 * 8;
    unsigned short* B3h = B2l + (size_t)F2 * 8;
    unsigned short* B3l = B3h + (size_t)F2 * 8;
    float* x3   = (float*)d_out;
    float* out  = (float*)d_out;

    const size_t aggBytes = (size_t)NN * ZD * sizeof(float);

    hipMemsetAsync(hist, 0, 20480 * sizeof(int), stream);
    hist_kernel<<<(NE + 255) / 256, 256, 0, stream>>>(dst, hist);
    scan_kernel<<<1, 1024, 0, stream>>>(hist, curs);
    scatter_kernel<<<(NE + 255) / 256, 256, 0, stream>>>(src, dst, curs, src_s, dst_s, perm);
    pack_w<<<(F1 + 255) / 256, 256, 0, stream>>>(Wm1, 196, F1, B1h, B1l);
    pack_w<<<(F2 + 255) / 256, 256, 0, stream>>>(Wm2, 388, F2, B2h, B2l);
    pack_w<<<(F2 + 255) / 256, 256, 0, stream>>>(Wm3, 388, F2, B3h, B3l);

    const int EG = NE / 64;        // 5000
    const int NG32 = NN / 32;      // 625 exact

    // conv1
    hipMemsetAsync(agg, 0, aggBytes, stream);
    edge_msg_mfma<64><<<EG, 256, 0, stream>>>(x, src_s, dst_s, perm, (const float4*)ea,
                                              B1h, B1l, bm1, agg);
    node_mlp32<64><<<NG32, 256, 0, stream>>>(x, agg, hist, Wf1, bf1, x1);

    // conv2
    hipMemsetAsync(agg, 0, aggBytes, stream);
    edge_msg_mfma<128><<<EG, 256, 0, stream>>>(x1, src_s, dst_s, perm, (const float4*)ea,
                                               B2h, B2l, bm2, agg);
    node_mlp32<128><<<NG32, 256, 0, stream>>>(x1, agg, hist, Wf2, bf2, x2);

    // conv3
    hipMemsetAsync(agg, 0, aggBytes, stream);
    edge_msg_mfma<128><<<EG, 256, 0, stream>>>(x2, src_s, dst_s, perm, (const float4*)ea,
                                               B3h, B3l, bm3, agg);
    node_mlp32<128><<<NG32, 256, 0, stream>>>(x2, agg, hist, Wf3, bf3, x3);

    // fusion
    fusion32<<<NG32, 256, 0, stream>>>(x1, x2, x3, Wl, bl, out);
}